// Round 11
// baseline (721.822 us; speedup 1.0000x reference)
//
#include <hip/hip_runtime.h>
#include <hip/hip_bf16.h>

#define NROWS 65536
#define KDIM  1024
#define NOUT  1024
#define NTYPE 8

typedef __attribute__((ext_vector_type(8))) short bf16x8;
typedef __attribute__((ext_vector_type(4))) float f32x4;

// RNE fp32 -> bf16 pack (2 values -> 1 dword), ~3 VALU per value
__device__ __forceinline__ unsigned int pk2_rn(float a, float b) {
  unsigned int ua = __float_as_uint(a);
  unsigned int ub = __float_as_uint(b);
  ua += 0x7fffu + ((ua >> 16) & 1u);
  ub += 0x7fffu + ((ub >> 16) & 1u);
  return (ua >> 16) | (ub & 0xffff0000u);
}

__device__ __forceinline__ void async_cp16(const void* g, void* l) {
  __builtin_amdgcn_global_load_lds(
      (const __attribute__((address_space(1))) unsigned int*)g,
      (__attribute__((address_space(3))) unsigned int*)l, 16, 0, 0);
}

// W fp32 [t][k][n] -> Wt bf16 [t][n][k], 16B blocks within each 64B k-group
// swizzled: block b stored at b ^ ((n>>1)&3).
// LDS-tiled transpose: 64k x 64n tile per block; coalesced float2 reads,
// bank-conflict-free u32 LDS writes (stride 66 shorts), full-line 16B stores.
__global__ __launch_bounds__(256) void wtrans_kernel(
    const float* __restrict__ W, unsigned short* __restrict__ Wt) {
  __shared__ unsigned short T[64 * 66];  // [n][k], row stride 66 shorts
  unsigned int* Tw = (unsigned int*)T;   // word idx = n*33 + k/2

  const int ty = blockIdx.x;
  const int k0 = blockIdx.y * 64;
  const int n0 = blockIdx.z * 64;
  const float* src = W + (size_t)ty * (KDIM * NOUT);
  unsigned short* dst = Wt + (size_t)ty * (KDIM * NOUT);

  const int tid = threadIdx.x;
  const int k2 = tid >> 5;  // 0..7  (pair of k rows)
  const int n2 = tid & 31;  // 0..31 (pair of n cols)

#pragma unroll
  for (int p = 0; p < 4; ++p) {
    int kl = p * 16 + k2 * 2;
    float2 v0 = *(const float2*)(src + (size_t)(k0 + kl) * NOUT + n0 + n2 * 2);
    float2 v1 = *(const float2*)(src + (size_t)(k0 + kl + 1) * NOUT + n0 + n2 * 2);
    // T[n][kl], T[n][kl+1] packed as one dword
    Tw[(n2 * 2) * 33 + p * 8 + k2]     = pk2_rn(v0.x, v1.x);
    Tw[(n2 * 2 + 1) * 33 + p * 8 + k2] = pk2_rn(v0.y, v1.y);
  }
  __syncthreads();

  const int c   = tid & 7;   // 16B block (8 k) within tile
  const int nl0 = tid >> 3;  // 0..31
#pragma unroll
  for (int p = 0; p < 2; ++p) {
    int nl = nl0 + p * 32;
    int ng = n0 + nl;
    const unsigned int* tw = Tw + nl * 33 + c * 4;
    uint4 o;
    o.x = tw[0]; o.y = tw[1]; o.z = tw[2]; o.w = tw[3];
    int kc = (k0 >> 3) + c;
    int G  = kc >> 2;
    int bp = (kc & 3) ^ ((ng >> 1) & 3);
    *(uint4*)(dst + (size_t)ng * KDIM + G * 32 + bp * 8) = o;
  }
}

// 128x128 tile, 256 threads (4 waves, 2x2 of 64x64), 16x16x32 bf16 MFMA.
// DUAL-SLAB stage: two independent BK=32 slabs (each with the PROVEN
// conflict-free 64B-stride layout, 0 bank conflicts measured) staged per
// barrier pair -> 32 MFMAs per stage, half the barriers of BK=32-single.
// Stage order: A fp32 loads first, B DMAs second (A-pack waits vmcnt(4)).
// XCD remap (proven: FETCH 5.7x down): each XCD owns a 64-row-tile band.
__global__ __launch_bounds__(256) void typed_gemm_kernel(
    const float* __restrict__ x, const int* __restrict__ types,
    const unsigned short* __restrict__ Wt, const float* __restrict__ bias,
    float* __restrict__ out) {
  __shared__ unsigned short As[2 * 128 * 32];  // slab kk at kk*4096 elements
  __shared__ unsigned short Bs[2 * 128 * 32];

  const int tid  = threadIdx.x;
  const int lane = tid & 63;
  const int wave = tid >> 6;
  const int quad = lane >> 4;
  const int l16  = lane & 15;

  // XCD-aware remap (bijective; nwg = 4096 = 8*512):
  // xcd = linear_id % 8; each XCD gets row-tiles [xcd*64, xcd*64+64), col fastest.
  const int wg   = blockIdx.y * gridDim.x + blockIdx.x;
  const int xcd  = wg & 7;
  const int idx  = wg >> 3;               // 0..511
  const int n0   = (idx & 7) * 128;
  const int m0   = ((xcd << 6) + (idx >> 3)) * 128;

  const int t0 = types[m0];
  const int t1 = types[m0 + 127];
  const bool multi = (t0 != t1);
  const int S = (t1 - t0 + 1) * 16;  // 64-k stages across the type range

  // Per-slab staged slots (identical pattern to the 0-conflict BK=32 kernel):
  // slot r (0..3): idx2 = r*256+tid -> m = idx2>>3 (0..127), kc = idx2&7.
  // Slots 4..7 are the same (m,kc) in slab 1 (k offset +32).
  int stype[4], aoff[4], agof[4];
#pragma unroll
  for (int r = 0; r < 4; ++r) {
    int idx2 = r * 256 + tid;
    int m  = idx2 >> 3;      // 0..127
    int kc = idx2 & 7;       // float4 chunk within slab BK=32
    stype[r] = types[m0 + m];
    int b  = kc >> 1;        // 16B block (8 bf16)
    int h  = kc & 1;         // which half of the block
    int bp = b ^ ((m >> 1) & 3);
    aoff[r] = m * 32 + bp * 8 + h * 4;   // elements within slab
    agof[r] = (m0 + m) * KDIM + kc * 4;  // float offset into x (slab 0)
  }

  const int mbase = (wave & 1) * 64;
  const int nbase = (wave >> 1) * 64;

  // LDS fragment read offsets (elements within slab), swizzle-corrected
  int ard[4], brd[4];
#pragma unroll
  for (int mt = 0; mt < 4; ++mt) {
    int m = mbase + mt * 16 + l16;
    ard[mt] = m * 32 + (quad ^ ((m >> 1) & 3)) * 8;
  }
#pragma unroll
  for (int nt = 0; nt < 4; ++nt) {
    int n = nbase + nt * 16 + l16;
    brd[nt] = n * 32 + (quad ^ ((n >> 1) & 3)) * 8;
  }

  f32x4 acc[4][4];
#pragma unroll
  for (int i = 0; i < 4; ++i)
#pragma unroll
    for (int j = 0; j < 4; ++j) acc[i][j] = (f32x4){0.f, 0.f, 0.f, 0.f};

  // B async-copy addressing: seg covers 16 n-rows (64B per row per slab)
  const int brow = lane >> 2;   // row within segment
  const int bchk = lane & 3;    // 16B chunk within 64B row

  for (int s = 0; s < S; ++s) {
    const int t  = t0 + (s >> 4);
    const int kb = (s & 15) << 6;  // k base (elements), 64 per stage

    // ---- stage phase ----
    // A fp32 loads FIRST (oldest in vmcnt queue -> pack waits vmcnt(4));
    // slots 0..3 = slab 0, slots 4..7 = slab 1 (k +32).
    float4 av[8];
#pragma unroll
    for (int r = 0; r < 8; ++r)
      av[r] = *(const float4*)(x + agof[r & 3] + (r >> 2) * 32 + kb);

    // B DMAs second: 4 per wave (2 slabs x 2 segments), each 16 rows x 64B.
    {
      const unsigned short* wbase = Wt + (size_t)t * (KDIM * NOUT);
#pragma unroll
      for (int j = 0; j < 4; ++j) {
        int kk  = j >> 1;
        int seg = wave * 2 + (j & 1);
        const unsigned short* g0 =
            wbase + (size_t)(n0 + seg * 16 + brow) * KDIM + kb + kk * 32 +
            bchk * 8;
        async_cp16(g0, &Bs[kk * 4096 + seg * 512 + lane * 8]);
      }
    }

    // A pack + type mask + 8B LDS writes (waits only on the A loads)
#pragma unroll
    for (int r = 0; r < 8; ++r) {
      uint2 p;
      p.x = pk2_rn(av[r].x, av[r].y);
      p.y = pk2_rn(av[r].z, av[r].w);
      if (stype[r & 3] != t) { p.x = 0u; p.y = 0u; }
      *(uint2*)(&As[(r >> 2) * 4096 + aoff[r & 3]]) = p;
    }
    __syncthreads();  // drains A ds_writes + B DMAs

    // ---- compute: 2 slabs x 16 MFMAs ----
#pragma unroll
    for (int kk = 0; kk < 2; ++kk) {
      bf16x8 af[4], bfr[4];
#pragma unroll
      for (int i = 0; i < 4; ++i)
        af[i] = *(const bf16x8*)(&As[kk * 4096 + ard[i]]);
#pragma unroll
      for (int i = 0; i < 4; ++i)
        bfr[i] = *(const bf16x8*)(&Bs[kk * 4096 + brd[i]]);
#pragma unroll
      for (int mt = 0; mt < 4; ++mt)
#pragma unroll
        for (int nt = 0; nt < 4; ++nt)
          acc[mt][nt] = __builtin_amdgcn_mfma_f32_16x16x32_bf16(
              af[mt], bfr[nt], acc[mt][nt], 0, 0, 0);
    }
    __syncthreads();  // LDS free for next stage
  }

  // ---- epilogue: add per-row bias, store fp32 ----
  // C/D layout: col = l16 (+nt*16), row = quad*4+reg (+mt*16)
  float bval[4];
  if (!multi) {
#pragma unroll
    for (int nt = 0; nt < 4; ++nt)
      bval[nt] = bias[t0 * NOUT + n0 + nbase + nt * 16 + l16];
  }
#pragma unroll
  for (int mt = 0; mt < 4; ++mt) {
#pragma unroll
    for (int reg = 0; reg < 4; ++reg) {
      int rl = mbase + mt * 16 + quad * 4 + reg;
      int grow = m0 + rl;
      float* orow = out + (size_t)grow * NOUT + n0 + nbase + l16;
      if (!multi) {
#pragma unroll
        for (int nt = 0; nt < 4; ++nt)
          orow[nt * 16] = acc[mt][nt][reg] + bval[nt];
      } else {
        int ty = types[grow];
#pragma unroll
        for (int nt = 0; nt < 4; ++nt)
          orow[nt * 16] =
              acc[mt][nt][reg] + bias[ty * NOUT + n0 + nbase + nt * 16 + l16];
      }
    }
  }
}

extern "C" void kernel_launch(void* const* d_in, const int* in_sizes, int n_in,
                              void* d_out, int out_size, void* d_ws,
                              size_t ws_size, hipStream_t stream) {
  const float* x     = (const float*)d_in[0];
  const int*   types = (const int*)d_in[1];
  const float* W     = (const float*)d_in[2];
  const float* b     = (const float*)d_in[3];
  float* out = (float*)d_out;
  unsigned short* Wt = (unsigned short*)d_ws;  // 8*1024*1024 bf16 = 16 MB

  // Rebuild Wt every call (d_ws is re-poisoned before each timed launch).
  wtrans_kernel<<<dim3(NTYPE, KDIM / 64, NOUT / 64), 256, 0, stream>>>(W, Wt);
  typed_gemm_kernel<<<dim3(NOUT / 128, NROWS / 128), 256, 0, stream>>>(
      x, types, Wt, b, out);
}

// Round 12
// 687.438 us; speedup vs baseline: 1.0500x; 1.0500x over previous
//
#include <hip/hip_runtime.h>
#include <hip/hip_bf16.h>

#define NROWS 65536
#define KDIM  1024
#define NOUT  1024
#define NTYPE 8

typedef __attribute__((ext_vector_type(8))) short bf16x8;
typedef __attribute__((ext_vector_type(4))) float f32x4;

// RNE fp32 -> bf16 pack (2 values -> 1 dword), ~3 VALU per value
__device__ __forceinline__ unsigned int pk2_rn(float a, float b) {
  unsigned int ua = __float_as_uint(a);
  unsigned int ub = __float_as_uint(b);
  ua += 0x7fffu + ((ua >> 16) & 1u);
  ub += 0x7fffu + ((ub >> 16) & 1u);
  return (ua >> 16) | (ub & 0xffff0000u);
}

__device__ __forceinline__ void async_cp16(const void* g, void* l) {
  __builtin_amdgcn_global_load_lds(
      (const __attribute__((address_space(1))) unsigned int*)g,
      (__attribute__((address_space(3))) unsigned int*)l, 16, 0, 0);
}

// W fp32 [t][k][n] -> Wt bf16 [t][n][k], 16B blocks within each 64B k-group
// swizzled: block b stored at b ^ ((n>>1)&3).
// LDS-tiled transpose: 64k x 64n tile per block; coalesced float2 reads,
// bank-conflict-free u32 LDS writes (stride 66 shorts), full-line 16B stores.
__global__ __launch_bounds__(256) void wtrans_kernel(
    const float* __restrict__ W, unsigned short* __restrict__ Wt) {
  __shared__ unsigned short T[64 * 66];  // [n][k], row stride 66 shorts
  unsigned int* Tw = (unsigned int*)T;   // word idx = n*33 + k/2

  const int ty = blockIdx.x;
  const int k0 = blockIdx.y * 64;
  const int n0 = blockIdx.z * 64;
  const float* src = W + (size_t)ty * (KDIM * NOUT);
  unsigned short* dst = Wt + (size_t)ty * (KDIM * NOUT);

  const int tid = threadIdx.x;
  const int k2 = tid >> 5;  // 0..7  (pair of k rows)
  const int n2 = tid & 31;  // 0..31 (pair of n cols)

#pragma unroll
  for (int p = 0; p < 4; ++p) {
    int kl = p * 16 + k2 * 2;
    float2 v0 = *(const float2*)(src + (size_t)(k0 + kl) * NOUT + n0 + n2 * 2);
    float2 v1 = *(const float2*)(src + (size_t)(k0 + kl + 1) * NOUT + n0 + n2 * 2);
    // T[n][kl], T[n][kl+1] packed as one dword
    Tw[(n2 * 2) * 33 + p * 8 + k2]     = pk2_rn(v0.x, v1.x);
    Tw[(n2 * 2 + 1) * 33 + p * 8 + k2] = pk2_rn(v0.y, v1.y);
  }
  __syncthreads();

  const int c   = tid & 7;   // 16B block (8 k) within tile
  const int nl0 = tid >> 3;  // 0..31
#pragma unroll
  for (int p = 0; p < 2; ++p) {
    int nl = nl0 + p * 32;
    int ng = n0 + nl;
    const unsigned int* tw = Tw + nl * 33 + c * 4;
    uint4 o;
    o.x = tw[0]; o.y = tw[1]; o.z = tw[2]; o.w = tw[3];
    int kc = (k0 >> 3) + c;
    int G  = kc >> 2;
    int bp = (kc & 3) ^ ((ng >> 1) & 3);
    *(uint4*)(dst + (size_t)ng * KDIM + G * 32 + bp * 8) = o;
  }
}

// EXACT 366us-champion structure: 128x128 tile, BK=32, 2 barriers/K-step,
// 16KB LDS, 256 threads (4 waves, 2x2 of 64x64), 16x16x32 bf16 MFMA.
// ONLY change vs champion: XCD band remap (isolated A/B of the mapping).
__global__ __launch_bounds__(256) void typed_gemm_kernel(
    const float* __restrict__ x, const int* __restrict__ types,
    const unsigned short* __restrict__ Wt, const float* __restrict__ bias,
    float* __restrict__ out) {
  __shared__ unsigned short As[128 * 32];  // [m][32k], swizzled 16B blocks
  __shared__ unsigned short Bs[128 * 32];  // [n][32k], swizzled 16B blocks

  const int tid  = threadIdx.x;
  const int lane = tid & 63;
  const int wave = tid >> 6;
  const int quad = lane >> 4;
  const int l16  = lane & 15;

  // ---- THE ONE CHANGE: band-XCD remap (vs champion's n0=bx*128,m0=by*128)
  const int wg   = blockIdx.y * gridDim.x + blockIdx.x;
  const int xcd  = wg & 7;
  const int idx  = wg >> 3;               // 0..511
  const int n0   = (idx & 7) * 128;
  const int m0   = ((xcd << 6) + (idx >> 3)) * 128;

  const int t0 = types[m0];
  const int t1 = types[m0 + 127];
  const bool multi = (t0 != t1);

  // This thread's 4 staged (row, k-chunk) slots are fixed across iterations.
  int srow[4], stype[4], aoff[4];
  const float* agp[4];
#pragma unroll
  for (int r = 0; r < 4; ++r) {
    int idx2 = r * 256 + tid;
    int m = idx2 >> 3;       // 0..127
    int kc = idx2 & 7;       // float4 chunk within BK=32
    srow[r]  = m;
    stype[r] = types[m0 + m];
    int b  = kc >> 1;        // 16B block (8 bf16)
    int h  = kc & 1;         // which half of the block
    int bp = b ^ ((m >> 1) & 3);
    aoff[r] = m * 32 + bp * 8 + h * 4;  // elements
    agp[r]  = x + (size_t)(m0 + m) * KDIM + kc * 4;
  }

  const int mbase = (wave & 1) * 64;
  const int nbase = (wave >> 1) * 64;

  // LDS fragment read offsets (elements), swizzle-corrected
  int ard[4], brd[4];
#pragma unroll
  for (int mt = 0; mt < 4; ++mt) {
    int m = mbase + mt * 16 + l16;
    ard[mt] = m * 32 + (quad ^ ((m >> 1) & 3)) * 8;
  }
#pragma unroll
  for (int nt = 0; nt < 4; ++nt) {
    int n = nbase + nt * 16 + l16;
    brd[nt] = n * 32 + (quad ^ ((n >> 1) & 3)) * 8;
  }

  f32x4 acc[4][4];
#pragma unroll
  for (int i = 0; i < 4; ++i)
#pragma unroll
    for (int j = 0; j < 4; ++j) acc[i][j] = (f32x4){0.f, 0.f, 0.f, 0.f};

  // B async-copy addressing: seg = wave*2+c covers 16 n-rows (64B per row)
  const int brow = lane >> 2;   // row within segment
  const int bchk = lane & 3;    // 16B chunk within 64B row

  for (int t = t0; t <= t1; ++t) {
    const unsigned short* wbase = Wt + (size_t)t * (KDIM * NOUT);
    bool msk[4];
#pragma unroll
    for (int r = 0; r < 4; ++r) msk[r] = (stype[r] == t);

    for (int kb = 0; kb < KDIM; kb += 32) {
      // ---- stage B via global->LDS DMA (raw copy preserves swizzle) ----
      {
        int seg0 = wave * 2;
        int seg1 = seg0 + 1;
        const unsigned short* g0 =
            wbase + (size_t)(n0 + seg0 * 16 + brow) * KDIM + kb + bchk * 8;
        const unsigned short* g1 =
            wbase + (size_t)(n0 + seg1 * 16 + brow) * KDIM + kb + bchk * 8;
        async_cp16(g0, &Bs[seg0 * 512 + lane * 8]);
        async_cp16(g1, &Bs[seg1 * 512 + lane * 8]);
      }
      // ---- stage A: fp32 load, RNE->bf16, type mask, 8B LDS write ----
#pragma unroll
      for (int r = 0; r < 4; ++r) {
        float4 v = *(const float4*)(agp[r] + kb);
        uint2 p;
        p.x = pk2_rn(v.x, v.y);
        p.y = pk2_rn(v.z, v.w);
        if (!msk[r]) { p.x = 0u; p.y = 0u; }
        *(uint2*)(&As[aoff[r]]) = p;
      }
      __syncthreads();

      bf16x8 af[4], bfr[4];
#pragma unroll
      for (int i = 0; i < 4; ++i) af[i] = *(const bf16x8*)(&As[ard[i]]);
#pragma unroll
      for (int i = 0; i < 4; ++i) bfr[i] = *(const bf16x8*)(&Bs[brd[i]]);
#pragma unroll
      for (int mt = 0; mt < 4; ++mt)
#pragma unroll
        for (int nt = 0; nt < 4; ++nt)
          acc[mt][nt] = __builtin_amdgcn_mfma_f32_16x16x32_bf16(
              af[mt], bfr[nt], acc[mt][nt], 0, 0, 0);
      __syncthreads();
    }
  }

  // ---- epilogue: add per-row bias, store fp32 ----
  // C/D layout: col = l16 (+nt*16), row = quad*4+reg (+mt*16)
  float bval[4];
  if (!multi) {
#pragma unroll
    for (int nt = 0; nt < 4; ++nt)
      bval[nt] = bias[t0 * NOUT + n0 + nbase + nt * 16 + l16];
  }
#pragma unroll
  for (int mt = 0; mt < 4; ++mt) {
#pragma unroll
    for (int reg = 0; reg < 4; ++reg) {
      int rl = mbase + mt * 16 + quad * 4 + reg;
      int grow = m0 + rl;
      float* orow = out + (size_t)grow * NOUT + n0 + nbase + l16;
      if (!multi) {
#pragma unroll
        for (int nt = 0; nt < 4; ++nt)
          orow[nt * 16] = acc[mt][nt][reg] + bval[nt];
      } else {
        int ty = types[grow];
#pragma unroll
        for (int nt = 0; nt < 4; ++nt)
          orow[nt * 16] =
              acc[mt][nt][reg] + bias[ty * NOUT + n0 + nbase + nt * 16 + l16];
      }
    }
  }
}

extern "C" void kernel_launch(void* const* d_in, const int* in_sizes, int n_in,
                              void* d_out, int out_size, void* d_ws,
                              size_t ws_size, hipStream_t stream) {
  const float* x     = (const float*)d_in[0];
  const int*   types = (const int*)d_in[1];
  const float* W     = (const float*)d_in[2];
  const float* b     = (const float*)d_in[3];
  float* out = (float*)d_out;
  unsigned short* Wt = (unsigned short*)d_ws;  // 8*1024*1024 bf16 = 16 MB

  // Rebuild Wt every call (d_ws is re-poisoned before each timed launch).
  wtrans_kernel<<<dim3(NTYPE, KDIM / 64, NOUT / 64), 256, 0, stream>>>(W, Wt);
  typed_gemm_kernel<<<dim3(NOUT / 128, NROWS / 128), 256, 0, stream>>>(
      x, types, Wt, b, out);
}